// Round 13
// baseline (56.942 us; speedup 1.0000x reference)
//
#include <hip/hip_runtime.h>

// GCN layer: out[i,:] = relu( dinv[i] * sum_{e: dst=i} dinv[src_e] * x[src_e,:] )
// dinv[i] = indeg>0 ? indeg^-1/2 : 0
//
// Primary path (4 dispatches):
//   K0 k_zero_cur: zero per-bucket cursors (391 ints).
//   K1 k_sort_conv: [blocks <SORTB] LDS counting-sort of edge chunks by 128-node
//      bucket (word=(d<<16)|s), ONE global atomic per (block,bucket), coalesced
//      segment write.  [blocks >=SORTB] x fp32->bf16 convert (CONCURRENT).
//   K2 k_finseg: one block per bucket, read bucket ONCE: per-node hist -> scan ->
//      seg(start,end) + dinv + node-sorted ushort src stream (coalesced write).
//   K3 k_gather: 8 nodes/block, 32 lanes/node (2 edges/step, unroll 4),
//      shfl_xor(16) fold, one float4 store per lane. Balanced: wave = 2 nodes.
// Fallbacks: direct padded-atomic path; last-resort atomic scatter.

#define SORTB    384   // sort blocks
#define CHUNKMAX 2368  // max edges per sort block
#define NBP      512   // padded bucket count (supports n <= 65536)
#define BCAP     2048  // bucket capacity (edges)

__device__ __forceinline__ int detect_is64(const unsigned int* w) {
    const int t = threadIdx.x & 63;
    unsigned long long m = __ballot(w[2 * t + 1] != 0u);
    return m == 0ull ? 1 : 0;
}

__device__ __forceinline__ int load_idx(const void* p, long long i, int is64) {
    return is64 ? (int)((const long long*)p)[i] : ((const int*)p)[i];
}

__device__ __forceinline__ unsigned short f2bf(float f) {
    unsigned u = __float_as_uint(f);
    unsigned r = (u + 0x7fffu + ((u >> 16) & 1u)) >> 16;  // RNE; inputs finite
    return (unsigned short)r;
}

__global__ void k_zero_cur(int* cursor, int nb) {
    for (int i = threadIdx.x; i < nb; i += blockDim.x) cursor[i] = 0;
}

__global__ void __launch_bounds__(256) k_zero(int4* p, int n4) {
    const int stride = gridDim.x * blockDim.x;
    for (int i = blockIdx.x * blockDim.x + threadIdx.x; i < n4; i += stride)
        p[i] = make_int4(0, 0, 0, 0);
}

// ---------------- primary path ----------------

// K1: per-chunk LDS counting sort by bucket (d>>7) || bf16 convert on extra blocks.
__global__ void __launch_bounds__(256) k_sort_conv(const void* ei, int* cursor,
                                                   unsigned int* __restrict__ buckets,
                                                   const float* __restrict__ x,
                                                   unsigned short* __restrict__ xb,
                                                   int E, int CH, int nconv) {
    const int bid = blockIdx.x;
    if (bid < SORTB) {
        __shared__ unsigned int raw[CHUNKMAX];
        __shared__ unsigned int srt[CHUNKMAX];
        __shared__ int hist[NBP];
        __shared__ int lbase[NBP];
        __shared__ int gbase[NBP];
        __shared__ int lcur[NBP];
        const int t = threadIdx.x;
        for (int i = t; i < NBP; i += 256) hist[i] = 0;
        __syncthreads();
        const int is64 = detect_is64((const unsigned int*)ei);
        const int e0 = bid * CH;
        const int e1 = min(e0 + CH, E);
        const int nch = e1 - e0;
        for (int i = t; i < nch; i += 256) {
            const long long e = e0 + i;
            int s = load_idx(ei, e, is64);
            int d = load_idx(ei, (long long)E + e, is64);
            unsigned w = ((unsigned)d << 16) | (unsigned)s;
            raw[i] = w;
            atomicAdd(&hist[d >> 7], 1);
        }
        __syncthreads();
        // exclusive scan of hist[0..NBP) by wave 0 (64 lanes x 8 elems)
        if (t < 64) {
            const int base = t * 8;
            int v[8];
            int sum = 0;
            #pragma unroll
            for (int k = 0; k < 8; ++k) { v[k] = hist[base + k]; sum += v[k]; }
            int pre = sum;
            for (int off = 1; off < 64; off <<= 1) {
                int u = __shfl_up(pre, off);
                if (t >= off) pre += u;
            }
            pre -= sum;  // exclusive
            #pragma unroll
            for (int k = 0; k < 8; ++k) { lbase[base + k] = pre; pre += v[k]; }
        }
        __syncthreads();
        // one global atomic per non-empty (block, bucket)
        for (int b = t; b < NBP; b += 256) {
            const int c = hist[b];
            gbase[b] = c ? atomicAdd(&cursor[b], c) : 0;
            lcur[b] = lbase[b];
        }
        __syncthreads();
        // scatter into sorted LDS order
        for (int i = t; i < nch; i += 256) {
            const unsigned w = raw[i];
            const int p = atomicAdd(&lcur[w >> 23], 1);
            srt[p] = w;
        }
        __syncthreads();
        // linear (coalesced) write: segment-contiguous global positions
        for (int i = t; i < nch; i += 256) {
            const unsigned w = srt[i];
            const int b = w >> 23;
            const int g = gbase[b] + (i - lbase[b]);
            if (g < BCAP) buckets[(size_t)b * BCAP + g] = w;
        }
    } else if (xb) {
        const long long tid = (long long)(bid - SORTB) * 256 + threadIdx.x;
        if (tid < nconv) {
            const long long i = tid * 8;
            float4 a = *(const float4*)(x + i);
            float4 b = *(const float4*)(x + i + 4);
            union { unsigned short us[8]; uint4 v; } o;
            o.us[0] = f2bf(a.x); o.us[1] = f2bf(a.y); o.us[2] = f2bf(a.z); o.us[3] = f2bf(a.w);
            o.us[4] = f2bf(b.x); o.us[5] = f2bf(b.y); o.us[6] = f2bf(b.z); o.us[7] = f2bf(b.w);
            *(uint4*)(xb + i) = o.v;
        }
    }
}

// K2: one block per bucket, single scan: seg + dinv + node-sorted ushort srcs.
__global__ void __launch_bounds__(256) k_finseg(const unsigned int* __restrict__ buckets,
                                                const int* __restrict__ cursor,
                                                unsigned short* __restrict__ srcs,
                                                int2* __restrict__ seg,
                                                float* __restrict__ dinv, int n) {
    const int b = blockIdx.x;
    __shared__ unsigned int raw[BCAP];       // 8KB
    __shared__ unsigned short ss[BCAP];      // 4KB
    __shared__ int hist[128], base[128], lcur[128];
    const int t = threadIdx.x;
    if (t < 128) hist[t] = 0;
    __syncthreads();
    const int len = min(cursor[b], BCAP);
    const unsigned int* bb = buckets + (size_t)b * BCAP;
    for (int i = t; i < len; i += 256) {
        const unsigned w = bb[i];
        raw[i] = w;
        atomicAdd(&hist[(w >> 16) & 127], 1);
    }
    __syncthreads();
    if (t < 64) {
        const int v0 = hist[2 * t], v1 = hist[2 * t + 1];
        const int sum = v0 + v1;
        int pre = sum;
        for (int off = 1; off < 64; off <<= 1) {
            int u = __shfl_up(pre, off);
            if (t >= off) pre += u;
        }
        pre -= sum;  // exclusive
        base[2 * t] = pre;  base[2 * t + 1] = pre + v0;
        lcur[2 * t] = pre;  lcur[2 * t + 1] = pre + v0;
    }
    __syncthreads();
    if (t < 128) {
        const int node = b * 128 + t;
        if (node < n) {
            const int c = hist[t];
            seg[node] = make_int2(b * BCAP + base[t], b * BCAP + base[t] + c);
            dinv[node] = (c > 0) ? rsqrtf((float)c) : 0.f;
        }
    }
    __syncthreads();
    for (int i = t; i < len; i += 256) {
        const unsigned w = raw[i];
        const int p = atomicAdd(&lcur[(w >> 16) & 127], 1);
        ss[p] = (unsigned short)(w & 0xffffu);
    }
    __syncthreads();
    unsigned short* so = srcs + (size_t)b * BCAP;
    for (int i = t; i < len; i += 256) so[i] = ss[i];
}

// K3: gather. 8 nodes/block, 32 lanes/node (2 edges per step), unroll 4,
//     shfl_xor(16) fold, one float4 store per lane.
__global__ void __launch_bounds__(256) k_gather(const unsigned short* __restrict__ srcs,
                                                const int2* __restrict__ seg,
                                                const unsigned short* __restrict__ xb,
                                                const float* __restrict__ dinv,
                                                float* __restrict__ out, int n) {
    const int node = blockIdx.x * 8 + (threadIdx.x >> 5);
    if (node >= n) return;
    const int sl  = threadIdx.x & 15;        // feature sub-lane (8 cols)
    const int grp = (threadIdx.x >> 4) & 1;  // edge parity within node group
    const int2 sg = seg[node];
    const int eend = sg.y;
    const int deg = eend - sg.x;
    float acc[8] = {0.f, 0.f, 0.f, 0.f, 0.f, 0.f, 0.f, 0.f};

    auto addv = [&](uint4 v, float w) {
        acc[0] += w * __uint_as_float(v.x << 16);
        acc[1] += w * __uint_as_float(v.x & 0xffff0000u);
        acc[2] += w * __uint_as_float(v.y << 16);
        acc[3] += w * __uint_as_float(v.y & 0xffff0000u);
        acc[4] += w * __uint_as_float(v.z << 16);
        acc[5] += w * __uint_as_float(v.z & 0xffff0000u);
        acc[6] += w * __uint_as_float(v.w << 16);
        acc[7] += w * __uint_as_float(v.w & 0xffff0000u);
    };

    int e = sg.x + grp;   // this half-group handles edges of its parity
    for (; e + 6 < eend; e += 8) {           // 4 edges per lane per iter
        const int s0 = srcs[e],     s1 = srcs[e + 2];
        const int s2 = srcs[e + 4], s3 = srcs[e + 6];
        const float w0 = dinv[s0], w1 = dinv[s1], w2 = dinv[s2], w3 = dinv[s3];
        uint4 v0 = ((const uint4*)(xb + (size_t)s0 * 128))[sl];
        uint4 v1 = ((const uint4*)(xb + (size_t)s1 * 128))[sl];
        uint4 v2 = ((const uint4*)(xb + (size_t)s2 * 128))[sl];
        uint4 v3 = ((const uint4*)(xb + (size_t)s3 * 128))[sl];
        addv(v0, w0); addv(v1, w1); addv(v2, w2); addv(v3, w3);
    }
    for (; e < eend; e += 2) {
        const int s0 = srcs[e];
        addv(((const uint4*)(xb + (size_t)s0 * 128))[sl], dinv[s0]);
    }

    // fold the two edge-parity halves (lane ^ 16 stays inside the 32-lane group)
    #pragma unroll
    for (int k = 0; k < 8; ++k) acc[k] += __shfl_xor(acc[k], 16);

    const float dd = (deg > 0) ? rsqrtf((float)deg) : 0.f;
    float4 o;
    o.x = fmaxf(dd * (grp ? acc[4] : acc[0]), 0.f);
    o.y = fmaxf(dd * (grp ? acc[5] : acc[1]), 0.f);
    o.z = fmaxf(dd * (grp ? acc[6] : acc[2]), 0.f);
    o.w = fmaxf(dd * (grp ? acc[7] : acc[3]), 0.f);
    ((float4*)(out + (size_t)node * 128))[sl * 2 + grp] = o;
}

// ---------------- direct fallback (smaller ws) ----------------

__global__ void k_fill_direct(const void* ei, int* cnt, int* edges, int E, int cap) {
    const int is64 = detect_is64((const unsigned int*)ei);
    const int stride = gridDim.x * blockDim.x;
    for (int e = blockIdx.x * blockDim.x + threadIdx.x; e < E; e += stride) {
        int s = load_idx(ei, e, is64);
        int d = load_idx(ei, (long long)E + e, is64);
        int pos = atomicAdd(&cnt[d], 1);
        if (pos < cap) edges[(long long)d * cap + pos] = s;
    }
}

__global__ void __launch_bounds__(256) k_gather_pad(const float* __restrict__ x,
                                                    const int* __restrict__ edges,
                                                    const int* __restrict__ cnt,
                                                    float* __restrict__ out, int n, int cap) {
    const int node = blockIdx.x * 8 + (threadIdx.x >> 5);
    if (node >= n) return;
    const int lane = threadIdx.x & 31;
    const int m0 = cnt[node];
    const int m = min(m0, cap);
    const int* eb = edges + (long long)node * cap;
    float ax = 0.f, ay = 0.f, az = 0.f, aw = 0.f;
    int e = 0;
    for (; e + 3 < m; e += 4) {
        int s0 = eb[e], s1 = eb[e + 1], s2 = eb[e + 2], s3 = eb[e + 3];
        int c0 = cnt[s0], c1 = cnt[s1], c2 = cnt[s2], c3 = cnt[s3];
        float4 v0 = *(const float4*)(x + (long long)s0 * 128 + lane * 4);
        float4 v1 = *(const float4*)(x + (long long)s1 * 128 + lane * 4);
        float4 v2 = *(const float4*)(x + (long long)s2 * 128 + lane * 4);
        float4 v3 = *(const float4*)(x + (long long)s3 * 128 + lane * 4);
        float w0 = c0 > 0 ? rsqrtf((float)c0) : 0.f;
        float w1 = c1 > 0 ? rsqrtf((float)c1) : 0.f;
        float w2 = c2 > 0 ? rsqrtf((float)c2) : 0.f;
        float w3 = c3 > 0 ? rsqrtf((float)c3) : 0.f;
        ax += w0 * v0.x + w1 * v1.x + w2 * v2.x + w3 * v3.x;
        ay += w0 * v0.y + w1 * v1.y + w2 * v2.y + w3 * v3.y;
        az += w0 * v0.z + w1 * v1.z + w2 * v2.z + w3 * v3.z;
        aw += w0 * v0.w + w1 * v1.w + w2 * v2.w + w3 * v3.w;
    }
    for (; e < m; ++e) {
        int s0 = eb[e];
        int c0 = cnt[s0];
        float4 v0 = *(const float4*)(x + (long long)s0 * 128 + lane * 4);
        float w0 = c0 > 0 ? rsqrtf((float)c0) : 0.f;
        ax += w0 * v0.x; ay += w0 * v0.y; az += w0 * v0.z; aw += w0 * v0.w;
    }
    const float dd = m0 > 0 ? rsqrtf((float)m0) : 0.f;
    float4 rr;
    rr.x = fmaxf(dd * ax, 0.f); rr.y = fmaxf(dd * ay, 0.f);
    rr.z = fmaxf(dd * az, 0.f); rr.w = fmaxf(dd * aw, 0.f);
    *(float4*)(out + (long long)node * 128 + lane * 4) = rr;
}

// ---------------- last-resort atomic scatter (near-zero ws) ----------------

__global__ void k_deg_simple(const void* ei, float* deg, int E) {
    const int is64 = detect_is64((const unsigned int*)ei);
    const int stride = gridDim.x * blockDim.x;
    for (int e = blockIdx.x * blockDim.x + threadIdx.x; e < E; e += stride)
        atomicAdd(&deg[load_idx(ei, (long long)E + e, is64)], 1.0f);
}
__global__ void k_dinv_simple(float* deg, int n) {
    int i = blockIdx.x * blockDim.x + threadIdx.x;
    if (i < n) { float d = deg[i]; deg[i] = d > 0.f ? rsqrtf(d) : 0.f; }
}
__global__ void k_scatter_atomic(const float* __restrict__ x, const void* ei,
                                 const float* __restrict__ dinv, float* out, int E) {
    const int is64 = detect_is64((const unsigned int*)ei);
    const int lane = threadIdx.x & 31;
    const int eslot = threadIdx.x >> 5;
    const int stride = gridDim.x * 8;
    for (int e = blockIdx.x * 8 + eslot; e < E; e += stride) {
        int s = load_idx(ei, e, is64);
        int d = load_idx(ei, (long long)E + e, is64);
        float norm = dinv[s] * dinv[d];
        float4 v = ((const float4*)(x + (long long)s * 128))[lane];
        float* o = out + (long long)d * 128 + lane * 4;
        atomicAdd(o + 0, norm * v.x); atomicAdd(o + 1, norm * v.y);
        atomicAdd(o + 2, norm * v.z); atomicAdd(o + 3, norm * v.w);
    }
}
__global__ void k_relu4(float4* out, int n4) {
    const int stride = gridDim.x * blockDim.x;
    for (int i = blockIdx.x * blockDim.x + threadIdx.x; i < n4; i += stride) {
        float4 v = out[i];
        v.x = fmaxf(v.x, 0.f); v.y = fmaxf(v.y, 0.f);
        v.z = fmaxf(v.z, 0.f); v.w = fmaxf(v.w, 0.f);
        out[i] = v;
    }
}

extern "C" void kernel_launch(void* const* d_in, const int* in_sizes, int n_in,
                              void* d_out, int out_size, void* d_ws, size_t ws_size,
                              hipStream_t stream) {
    const float* x = (const float*)d_in[0];
    const void* ei = d_in[1];
    const int D = 128;
    const int n = in_sizes[0] / D;   // 50000
    const int E = in_sizes[1] / 2;   // 600000

    char* ws = (char*)d_ws;
    size_t off = 0;
    auto alloc = [&](size_t bytes) {
        char* p = ws + off;
        off += (bytes + 255) & ~(size_t)255;
        return p;
    };
    auto al = [](size_t b) { return (b + 255) & ~(size_t)255; };

    const int nb = (n + 127) / 128;                  // 391 buckets
    const int CH = (E + SORTB - 1) / SORTB;          // 1563
    const size_t szCur = al((size_t)nb * 4);
    const size_t szBkt = al((size_t)nb * BCAP * 4);  // 3.2MB
    const size_t szSrc = al((size_t)nb * BCAP * 2);  // 1.6MB
    const size_t szSeg = al((size_t)n * 8);          // 400KB
    const size_t szDnv = al((size_t)n * 4);          // 200KB
    const size_t szXb  = al((size_t)n * D * 2);      // 12.8MB
    const size_t needS = szCur + szBkt + szSrc + szSeg + szDnv + szXb;

    if (n <= 65536 && CH <= CHUNKMAX && nb <= NBP && ws_size >= needS) {
        int* cursor = (int*)alloc(szCur);
        unsigned int* buckets = (unsigned int*)alloc(szBkt);
        unsigned short* srcs = (unsigned short*)alloc(szSrc);
        int2* seg = (int2*)alloc(szSeg);
        float* dinv = (float*)alloc(szDnv);
        unsigned short* xb = (unsigned short*)alloc(szXb);

        k_zero_cur<<<1, 512, 0, stream>>>(cursor, nb);
        const int nconv = n * D / 8;  // 800000
        const int grid1 = SORTB + (nconv + 255) / 256;
        k_sort_conv<<<grid1, 256, 0, stream>>>(ei, cursor, buckets, x, xb, E, CH, nconv);
        k_finseg<<<nb, 256, 0, stream>>>(buckets, cursor, srcs, seg, dinv, n);
        k_gather<<<(n + 7) / 8, 256, 0, stream>>>(srcs, seg, xb, dinv, (float*)d_out, n);
        return;
    }

    // direct fallback
    auto needD = [&](int c) { return al((size_t)n * 4) + al((size_t)n * c * 4); };
    if (ws_size >= needD(48)) {
        int c = (ws_size >= needD(64)) ? 64 : 48;
        int* cnt   = (int*)alloc((size_t)n * 4);
        int* edges = (int*)alloc((size_t)n * c * 4);
        k_zero<<<(n / 4 + 255) / 256, 256, 0, stream>>>((int4*)cnt, n / 4);
        k_fill_direct<<<2048, 256, 0, stream>>>(ei, cnt, edges, E, c);
        k_gather_pad<<<(n + 7) / 8, 256, 0, stream>>>(x, edges, cnt, (float*)d_out, n, c);
        return;
    }

    // last resort: atomic scatter
    float* deg = (float*)alloc((size_t)n * 4);
    hipMemsetAsync(deg, 0, (size_t)n * sizeof(float), stream);
    hipMemsetAsync(d_out, 0, (size_t)out_size * sizeof(float), stream);
    k_deg_simple<<<2048, 256, 0, stream>>>(ei, deg, E);
    k_dinv_simple<<<(n + 255) / 256, 256, 0, stream>>>(deg, n);
    k_scatter_atomic<<<4096, 256, 0, stream>>>(x, ei, deg, (float*)d_out, E);
    k_relu4<<<2048, 256, 0, stream>>>((float4*)d_out, out_size / 4);
}

// Round 14
// 53.469 us; speedup vs baseline: 1.0650x; 1.0650x over previous
//
#include <hip/hip_runtime.h>

// GCN layer: out[i,:] = relu( dinv[i] * sum_{e: dst=i} dinv[src_e] * x[src_e,:] )
// dinv[i] = indeg>0 ? indeg^-1/2 : 0
//
// Primary path (4 dispatches):
//   K0 k_zero_cur: zero 8-way replicated per-bucket cursors.
//   K1 k_sort_conv: [blocks <SORTB] LDS counting-sort of edge chunks by 128-node
//      bucket (word=(d<<16)|s). Replicated cursors (r=bid&7) with FIXED
//      per-replica subregions kill gbase atomic serialization (48 vs 384 blocks
//      per address). Coalesced segment write. [blocks >=SORTB] fp32->bf16
//      convert (CONCURRENT - serializing it cost +4us in R10/R11).
//   K2 k_finseg: one block per bucket: read 8 sub-segments ONCE -> per-node hist
//      -> scan -> seg(start,end) + dinv + node-sorted ushort src stream.
//   K3 k_gather: 16 nodes/block, 16 lanes/node: pure loop {2B src bcast, 4B dinv
//      (L2-resident), 16B row, fma}, 8-deep unroll, fused rsqrt+relu. No LDS.
// Fallbacks: direct padded-atomic path; last-resort atomic scatter.

#define SORTB    512   // sort blocks
#define CHUNKMAX 1184  // max edges per sort block
#define NBP      512   // padded bucket count (supports n <= 65536)
#define SUBCAP   320   // per-replica subregion capacity
#define BSTRIDE  2560  // bucket stride = 8*SUBCAP
#define SCAP     2048  // srcs capacity per bucket

__device__ __forceinline__ int detect_is64(const unsigned int* w) {
    const int t = threadIdx.x & 63;
    unsigned long long m = __ballot(w[2 * t + 1] != 0u);
    return m == 0ull ? 1 : 0;
}

__device__ __forceinline__ int load_idx(const void* p, long long i, int is64) {
    return is64 ? (int)((const long long*)p)[i] : ((const int*)p)[i];
}

__device__ __forceinline__ unsigned short f2bf(float f) {
    unsigned u = __float_as_uint(f);
    unsigned r = (u + 0x7fffu + ((u >> 16) & 1u)) >> 16;  // RNE; inputs finite
    return (unsigned short)r;
}

__global__ void k_zero_cur(int* cursor, int ncur) {
    for (int i = threadIdx.x; i < ncur; i += blockDim.x) cursor[i] = 0;
}

__global__ void __launch_bounds__(256) k_zero(int4* p, int n4) {
    const int stride = gridDim.x * blockDim.x;
    for (int i = blockIdx.x * blockDim.x + threadIdx.x; i < n4; i += stride)
        p[i] = make_int4(0, 0, 0, 0);
}

// ---------------- primary path ----------------

// K1: per-chunk LDS counting sort by bucket (d>>7) || bf16 convert on extra blocks.
__global__ void __launch_bounds__(256) k_sort_conv(const void* ei, int* cursor,
                                                   unsigned int* __restrict__ buckets,
                                                   const float* __restrict__ x,
                                                   unsigned short* __restrict__ xb,
                                                   int E, int CH, int nconv) {
    const int bid = blockIdx.x;
    if (bid < SORTB) {
        __shared__ unsigned int raw[CHUNKMAX];
        __shared__ unsigned int srt[CHUNKMAX];
        __shared__ int hist[NBP];
        __shared__ int lbase[NBP];
        __shared__ int gbase[NBP];
        __shared__ int lcur[NBP];
        const int t = threadIdx.x;
        for (int i = t; i < NBP; i += 256) hist[i] = 0;
        __syncthreads();
        const int is64 = detect_is64((const unsigned int*)ei);
        const int e0 = bid * CH;
        const int e1 = min(e0 + CH, E);
        const int nch = e1 - e0;
        for (int i = t; i < nch; i += 256) {
            const long long e = e0 + i;
            int s = load_idx(ei, e, is64);
            int d = load_idx(ei, (long long)E + e, is64);
            unsigned w = ((unsigned)d << 16) | (unsigned)s;
            raw[i] = w;
            atomicAdd(&hist[d >> 7], 1);
        }
        __syncthreads();
        // exclusive scan of hist[0..NBP) by wave 0 (64 lanes x 8 elems)
        if (t < 64) {
            const int base = t * 8;
            int v[8];
            int sum = 0;
            #pragma unroll
            for (int k = 0; k < 8; ++k) { v[k] = hist[base + k]; sum += v[k]; }
            int pre = sum;
            for (int off = 1; off < 64; off <<= 1) {
                int u = __shfl_up(pre, off);
                if (t >= off) pre += u;
            }
            pre -= sum;  // exclusive
            #pragma unroll
            for (int k = 0; k < 8; ++k) { lbase[base + k] = pre; pre += v[k]; }
        }
        __syncthreads();
        // replicated-cursor allocation: contention domain = blocks with same bid&7
        const int r = bid & 7;
        int* mycur = cursor + r * NBP;
        for (int b = t; b < NBP; b += 256) {
            const int c = hist[b];
            gbase[b] = c ? atomicAdd(&mycur[b], c) : 0;
            lcur[b] = lbase[b];
        }
        __syncthreads();
        // scatter into sorted LDS order
        for (int i = t; i < nch; i += 256) {
            const unsigned w = raw[i];
            const int p = atomicAdd(&lcur[w >> 23], 1);
            srt[p] = w;
        }
        __syncthreads();
        // linear (coalesced) write into this replica's fixed subregion
        for (int i = t; i < nch; i += 256) {
            const unsigned w = srt[i];
            const int b = w >> 23;
            const int g = gbase[b] + (i - lbase[b]);
            if (g < SUBCAP)
                buckets[(size_t)b * BSTRIDE + r * SUBCAP + g] = w;
        }
    } else if (xb) {
        const long long tid = (long long)(bid - SORTB) * 256 + threadIdx.x;
        if (tid < nconv) {
            const long long i = tid * 8;
            float4 a = *(const float4*)(x + i);
            float4 b = *(const float4*)(x + i + 4);
            union { unsigned short us[8]; uint4 v; } o;
            o.us[0] = f2bf(a.x); o.us[1] = f2bf(a.y); o.us[2] = f2bf(a.z); o.us[3] = f2bf(a.w);
            o.us[4] = f2bf(b.x); o.us[5] = f2bf(b.y); o.us[6] = f2bf(b.z); o.us[7] = f2bf(b.w);
            *(uint4*)(xb + i) = o.v;
        }
    }
}

// K2: one block per bucket; read 8 sub-segments once: seg + dinv + sorted srcs.
__global__ void __launch_bounds__(256) k_finseg(const unsigned int* __restrict__ buckets,
                                                const int* __restrict__ cursor,
                                                unsigned short* __restrict__ srcs,
                                                int2* __restrict__ seg,
                                                float* __restrict__ dinv, int n) {
    const int b = blockIdx.x;
    __shared__ unsigned int raw[BSTRIDE];     // 10.2KB
    __shared__ unsigned short ss[BSTRIDE];    // 5.1KB
    __shared__ int hist[128], base[128], lcur[128];
    __shared__ int lens[8], offs[8], stotal;
    const int t = threadIdx.x;
    if (t < 128) hist[t] = 0;
    if (t < 8) lens[t] = min(cursor[t * NBP + b], SUBCAP);
    __syncthreads();
    if (t == 0) {
        int o = 0;
        #pragma unroll
        for (int r = 0; r < 8; ++r) { offs[r] = o; o += lens[r]; }
        stotal = o;
    }
    __syncthreads();
    const unsigned int* bb = buckets + (size_t)b * BSTRIDE;
    #pragma unroll
    for (int r = 0; r < 8; ++r) {
        const int lr = lens[r];
        const int orr = offs[r];
        for (int i = t; i < lr; i += 256) {
            const unsigned w = bb[r * SUBCAP + i];
            raw[orr + i] = w;
            atomicAdd(&hist[(w >> 16) & 127], 1);
        }
    }
    __syncthreads();
    if (t < 64) {
        const int v0 = hist[2 * t], v1 = hist[2 * t + 1];
        const int sum = v0 + v1;
        int pre = sum;
        for (int off = 1; off < 64; off <<= 1) {
            int u = __shfl_up(pre, off);
            if (t >= off) pre += u;
        }
        pre -= sum;  // exclusive
        base[2 * t] = pre;  base[2 * t + 1] = pre + v0;
        lcur[2 * t] = pre;  lcur[2 * t + 1] = pre + v0;
    }
    __syncthreads();
    if (t < 128) {
        const int node = b * 128 + t;
        if (node < n) {
            const int c = hist[t];
            const int s0 = min(base[t], SCAP);
            const int s1 = min(base[t] + c, SCAP);
            seg[node] = make_int2(b * SCAP + s0, b * SCAP + s1);
            dinv[node] = (c > 0) ? rsqrtf((float)c) : 0.f;
        }
    }
    __syncthreads();
    const int len = stotal;
    for (int i = t; i < len; i += 256) {
        const unsigned w = raw[i];
        const int p = atomicAdd(&lcur[(w >> 16) & 127], 1);
        if (p < BSTRIDE) ss[p] = (unsigned short)(w & 0xffffu);
    }
    __syncthreads();
    unsigned short* so = srcs + (size_t)b * SCAP;
    const int wlen = min(len, SCAP);
    for (int i = t; i < wlen; i += 256) so[i] = ss[i];
}

// K3: minimal gather. 16 nodes/block, 16 lanes/node, pure load+fma loop.
__global__ void __launch_bounds__(256) k_gather(const unsigned short* __restrict__ srcs,
                                                const int2* __restrict__ seg,
                                                const unsigned short* __restrict__ xb,
                                                const float* __restrict__ dinv,
                                                float* __restrict__ out, int n) {
    const int node = blockIdx.x * 16 + (threadIdx.x >> 4);
    if (node >= n) return;
    const int lane = threadIdx.x & 15;
    const int2 sg = seg[node];
    int e = sg.x;
    const int eend = sg.y;
    const int deg = eend - e;
    float acc[8] = {0.f, 0.f, 0.f, 0.f, 0.f, 0.f, 0.f, 0.f};

    auto addv = [&](uint4 v, float w) {
        acc[0] += w * __uint_as_float(v.x << 16);
        acc[1] += w * __uint_as_float(v.x & 0xffff0000u);
        acc[2] += w * __uint_as_float(v.y << 16);
        acc[3] += w * __uint_as_float(v.y & 0xffff0000u);
        acc[4] += w * __uint_as_float(v.z << 16);
        acc[5] += w * __uint_as_float(v.z & 0xffff0000u);
        acc[6] += w * __uint_as_float(v.w << 16);
        acc[7] += w * __uint_as_float(v.w & 0xffff0000u);
    };

    for (; e + 7 < eend; e += 8) {
        int s[8];
        float w[8];
        uint4 v[8];
        #pragma unroll
        for (int k = 0; k < 8; ++k) s[k] = srcs[e + k];
        #pragma unroll
        for (int k = 0; k < 8; ++k) w[k] = dinv[s[k]];
        #pragma unroll
        for (int k = 0; k < 8; ++k) v[k] = ((const uint4*)(xb + (size_t)s[k] * 128))[lane];
        #pragma unroll
        for (int k = 0; k < 8; ++k) addv(v[k], w[k]);
    }
    for (; e + 1 < eend; e += 2) {
        const int s0 = srcs[e], s1 = srcs[e + 1];
        const float w0 = dinv[s0], w1 = dinv[s1];
        uint4 v0 = ((const uint4*)(xb + (size_t)s0 * 128))[lane];
        uint4 v1 = ((const uint4*)(xb + (size_t)s1 * 128))[lane];
        addv(v0, w0); addv(v1, w1);
    }
    if (e < eend) {
        const int s0 = srcs[e];
        addv(((const uint4*)(xb + (size_t)s0 * 128))[lane], dinv[s0]);
    }

    const float dd = (deg > 0) ? rsqrtf((float)deg) : 0.f;
    float4 o0, o1;
    o0.x = fmaxf(dd * acc[0], 0.f); o0.y = fmaxf(dd * acc[1], 0.f);
    o0.z = fmaxf(dd * acc[2], 0.f); o0.w = fmaxf(dd * acc[3], 0.f);
    o1.x = fmaxf(dd * acc[4], 0.f); o1.y = fmaxf(dd * acc[5], 0.f);
    o1.z = fmaxf(dd * acc[6], 0.f); o1.w = fmaxf(dd * acc[7], 0.f);
    float4* op = (float4*)(out + (size_t)node * 128);
    op[lane * 2] = o0;
    op[lane * 2 + 1] = o1;
}

// ---------------- direct fallback (smaller ws) ----------------

__global__ void k_fill_direct(const void* ei, int* cnt, int* edges, int E, int cap) {
    const int is64 = detect_is64((const unsigned int*)ei);
    const int stride = gridDim.x * blockDim.x;
    for (int e = blockIdx.x * blockDim.x + threadIdx.x; e < E; e += stride) {
        int s = load_idx(ei, e, is64);
        int d = load_idx(ei, (long long)E + e, is64);
        int pos = atomicAdd(&cnt[d], 1);
        if (pos < cap) edges[(long long)d * cap + pos] = s;
    }
}

__global__ void __launch_bounds__(256) k_gather_pad(const float* __restrict__ x,
                                                    const int* __restrict__ edges,
                                                    const int* __restrict__ cnt,
                                                    float* __restrict__ out, int n, int cap) {
    const int node = blockIdx.x * 8 + (threadIdx.x >> 5);
    if (node >= n) return;
    const int lane = threadIdx.x & 31;
    const int m0 = cnt[node];
    const int m = min(m0, cap);
    const int* eb = edges + (long long)node * cap;
    float ax = 0.f, ay = 0.f, az = 0.f, aw = 0.f;
    int e = 0;
    for (; e + 3 < m; e += 4) {
        int s0 = eb[e], s1 = eb[e + 1], s2 = eb[e + 2], s3 = eb[e + 3];
        int c0 = cnt[s0], c1 = cnt[s1], c2 = cnt[s2], c3 = cnt[s3];
        float4 v0 = *(const float4*)(x + (long long)s0 * 128 + lane * 4);
        float4 v1 = *(const float4*)(x + (long long)s1 * 128 + lane * 4);
        float4 v2 = *(const float4*)(x + (long long)s2 * 128 + lane * 4);
        float4 v3 = *(const float4*)(x + (long long)s3 * 128 + lane * 4);
        float w0 = c0 > 0 ? rsqrtf((float)c0) : 0.f;
        float w1 = c1 > 0 ? rsqrtf((float)c1) : 0.f;
        float w2 = c2 > 0 ? rsqrtf((float)c2) : 0.f;
        float w3 = c3 > 0 ? rsqrtf((float)c3) : 0.f;
        ax += w0 * v0.x + w1 * v1.x + w2 * v2.x + w3 * v3.x;
        ay += w0 * v0.y + w1 * v1.y + w2 * v2.y + w3 * v3.y;
        az += w0 * v0.z + w1 * v1.z + w2 * v2.z + w3 * v3.z;
        aw += w0 * v0.w + w1 * v1.w + w2 * v2.w + w3 * v3.w;
    }
    for (; e < m; ++e) {
        int s0 = eb[e];
        int c0 = cnt[s0];
        float4 v0 = *(const float4*)(x + (long long)s0 * 128 + lane * 4);
        float w0 = c0 > 0 ? rsqrtf((float)c0) : 0.f;
        ax += w0 * v0.x; ay += w0 * v0.y; az += w0 * v0.z; aw += w0 * v0.w;
    }
    const float dd = m0 > 0 ? rsqrtf((float)m0) : 0.f;
    float4 rr;
    rr.x = fmaxf(dd * ax, 0.f); rr.y = fmaxf(dd * ay, 0.f);
    rr.z = fmaxf(dd * az, 0.f); rr.w = fmaxf(dd * aw, 0.f);
    *(float4*)(out + (long long)node * 128 + lane * 4) = rr;
}

// ---------------- last-resort atomic scatter (near-zero ws) ----------------

__global__ void k_deg_simple(const void* ei, float* deg, int E) {
    const int is64 = detect_is64((const unsigned int*)ei);
    const int stride = gridDim.x * blockDim.x;
    for (int e = blockIdx.x * blockDim.x + threadIdx.x; e < E; e += stride)
        atomicAdd(&deg[load_idx(ei, (long long)E + e, is64)], 1.0f);
}
__global__ void k_dinv_simple(float* deg, int n) {
    int i = blockIdx.x * blockDim.x + threadIdx.x;
    if (i < n) { float d = deg[i]; deg[i] = d > 0.f ? rsqrtf(d) : 0.f; }
}
__global__ void k_scatter_atomic(const float* __restrict__ x, const void* ei,
                                 const float* __restrict__ dinv, float* out, int E) {
    const int is64 = detect_is64((const unsigned int*)ei);
    const int lane = threadIdx.x & 31;
    const int eslot = threadIdx.x >> 5;
    const int stride = gridDim.x * 8;
    for (int e = blockIdx.x * 8 + eslot; e < E; e += stride) {
        int s = load_idx(ei, e, is64);
        int d = load_idx(ei, (long long)E + e, is64);
        float norm = dinv[s] * dinv[d];
        float4 v = ((const float4*)(x + (long long)s * 128))[lane];
        float* o = out + (long long)d * 128 + lane * 4;
        atomicAdd(o + 0, norm * v.x); atomicAdd(o + 1, norm * v.y);
        atomicAdd(o + 2, norm * v.z); atomicAdd(o + 3, norm * v.w);
    }
}
__global__ void k_relu4(float4* out, int n4) {
    const int stride = gridDim.x * blockDim.x;
    for (int i = blockIdx.x * blockDim.x + threadIdx.x; i < n4; i += stride) {
        float4 v = out[i];
        v.x = fmaxf(v.x, 0.f); v.y = fmaxf(v.y, 0.f);
        v.z = fmaxf(v.z, 0.f); v.w = fmaxf(v.w, 0.f);
        out[i] = v;
    }
}

extern "C" void kernel_launch(void* const* d_in, const int* in_sizes, int n_in,
                              void* d_out, int out_size, void* d_ws, size_t ws_size,
                              hipStream_t stream) {
    const float* x = (const float*)d_in[0];
    const void* ei = d_in[1];
    const int D = 128;
    const int n = in_sizes[0] / D;   // 50000
    const int E = in_sizes[1] / 2;   // 600000

    char* ws = (char*)d_ws;
    size_t off = 0;
    auto alloc = [&](size_t bytes) {
        char* p = ws + off;
        off += (bytes + 255) & ~(size_t)255;
        return p;
    };
    auto al = [](size_t b) { return (b + 255) & ~(size_t)255; };

    const int nb = (n + 127) / 128;                     // 391 buckets
    const int CH = (E + SORTB - 1) / SORTB;             // 1172
    const size_t szCur = al((size_t)8 * NBP * 4);       // 16KB
    const size_t szBkt = al((size_t)nb * BSTRIDE * 4);  // 4.0MB
    const size_t szSrc = al((size_t)nb * SCAP * 2);     // 1.6MB
    const size_t szSeg = al((size_t)n * 8);             // 400KB
    const size_t szDnv = al((size_t)n * 4);             // 200KB
    const size_t szXb  = al((size_t)n * D * 2);         // 12.8MB
    const size_t needS = szCur + szBkt + szSrc + szSeg + szDnv + szXb;

    if (n <= 65536 && CH <= CHUNKMAX && nb <= NBP && ws_size >= needS) {
        int* cursor = (int*)alloc(szCur);
        unsigned int* buckets = (unsigned int*)alloc(szBkt);
        unsigned short* srcs = (unsigned short*)alloc(szSrc);
        int2* seg = (int2*)alloc(szSeg);
        float* dinv = (float*)alloc(szDnv);
        unsigned short* xb = (unsigned short*)alloc(szXb);

        k_zero_cur<<<1, 1024, 0, stream>>>(cursor, 8 * NBP);
        const int nconv = n * D / 8;  // 800000
        const int grid1 = SORTB + (nconv + 255) / 256;
        k_sort_conv<<<grid1, 256, 0, stream>>>(ei, cursor, buckets, x, xb, E, CH, nconv);
        k_finseg<<<nb, 256, 0, stream>>>(buckets, cursor, srcs, seg, dinv, n);
        k_gather<<<(n + 15) / 16, 256, 0, stream>>>(srcs, seg, xb, dinv, (float*)d_out, n);
        return;
    }

    // direct fallback
    auto needD = [&](int c) { return al((size_t)n * 4) + al((size_t)n * c * 4); };
    if (ws_size >= needD(48)) {
        int c = (ws_size >= needD(64)) ? 64 : 48;
        int* cnt   = (int*)alloc((size_t)n * 4);
        int* edges = (int*)alloc((size_t)n * c * 4);
        k_zero<<<(n / 4 + 255) / 256, 256, 0, stream>>>((int4*)cnt, n / 4);
        k_fill_direct<<<2048, 256, 0, stream>>>(ei, cnt, edges, E, c);
        k_gather_pad<<<(n + 7) / 8, 256, 0, stream>>>(x, edges, cnt, (float*)d_out, n, c);
        return;
    }

    // last resort: atomic scatter
    float* deg = (float*)alloc((size_t)n * 4);
    hipMemsetAsync(deg, 0, (size_t)n * sizeof(float), stream);
    hipMemsetAsync(d_out, 0, (size_t)out_size * sizeof(float), stream);
    k_deg_simple<<<2048, 256, 0, stream>>>(ei, deg, E);
    k_dinv_simple<<<(n + 255) / 256, 256, 0, stream>>>(deg, n);
    k_scatter_atomic<<<4096, 256, 0, stream>>>(x, ei, deg, (float*)d_out, E);
    k_relu4<<<2048, 256, 0, stream>>>((float4*)d_out, out_size / 4);
}